// Round 11
// baseline (1099.942 us; speedup 1.0000x reference)
//
#include <hip/hip_runtime.h>
#include <hip/hip_cooperative_groups.h>
#include <math.h>

namespace cg = cooperative_groups;

#define NODES 20000
#define MPAD  20096          // NODES padded to multiple of 128 (GEMM M-tiles)
#define EDGES 320000
#define EPSV  1e-5f
#define LOG2E 1.4426950408889634f

typedef short bf16x8 __attribute__((ext_vector_type(8)));
typedef float f32x4  __attribute__((ext_vector_type(4)));
typedef float f2     __attribute__((ext_vector_type(2)));

__device__ __forceinline__ unsigned short f2bf(float f) {
    unsigned int u = __float_as_uint(f);
    u = (u + 0x7fffu + ((u >> 16) & 1u)) >> 16;
    return (unsigned short)u;
}
__device__ __forceinline__ float bf2f(unsigned short h) {
    return __uint_as_float(((unsigned int)h) << 16);
}

// async global->LDS, 16B per lane; lds dest = wave-uniform base + lane*16
__device__ __forceinline__ void load_lds16(const unsigned short* g, unsigned short* l) {
    __builtin_amdgcn_global_load_lds(
        (const __attribute__((address_space(1))) unsigned int*)g,
        (__attribute__((address_space(3))) unsigned int*)l, 16, 0, 0);
}

// one LDS arena shared by all phases (phases separated by grid.sync)
union SMem {
    struct { short As[128 * 32]; short Bs[128 * 32]; float rs[256]; float rq[256]; } g;
    float tile[32][33];   // weight transpose
    int   ssum[256];      // CSR scan
    float p[256];         // final head
};

struct Params {
    const int *src, *dst;
    const float *x;
    const float *t1, *bl1, *g1, *be1;
    const float *t2, *bl2, *g2, *be2;
    const float *Wl1, *Wr1, *Wl2, *Wr2;
    const float *Wf, *bf, *gx, *bx;
    float* out;
    int *counts, *offs, *csrc;
    float *acc, *colsum;
    unsigned short *w1lt, *w1rt, *w2lt, *w2rt;
    unsigned short *xb, *aggb, *h1, *h2p;
};

// ------- per-channel softmax aggregation (un-stabilized; inputs bounded) -----
// S waves per node; wave-uniform CSR walk (readfirstlane -> s_load of csr);
// vector pipe: loop-invariant-offset gather + packed-f32 exp2/fma.
template <int C, int S, int UNR>
__device__ __forceinline__ void agg_phase(const unsigned short* __restrict__ xb,
                                          const float* __restrict__ tt,
                                          const int* __restrict__ offs,
                                          const int* __restrict__ csr,
                                          unsigned short* __restrict__ out,
                                          int gwave, int nwaves) {
    constexpr int CS  = C / S;
    constexpr int VPL = CS / 64;
    constexpr int W   = VPL / 2;
    typedef unsigned int uv __attribute__((ext_vector_type(W)));
    typedef unsigned short usv __attribute__((ext_vector_type(VPL)));
    int lane = threadIdx.x & 63;
    for (int wt = gwave; wt < NODES * S; wt += nwaves) {
        int node = wt / S, slice = wt % S;
        int beg = __builtin_amdgcn_readfirstlane(offs[node]);
        int end = __builtin_amdgcn_readfirstlane(offs[node + 1]);
        int cb = slice * CS + lane * VPL;
        const unsigned short* __restrict__ xcb = xb + cb;
        f2 tl[W], l[W], s[W];
#pragma unroll
        for (int i = 0; i < W; i++) {
            tl[i][0] = tt[cb + 2 * i] * LOG2E;
            tl[i][1] = tt[cb + 2 * i + 1] * LOG2E;
            l[i][0] = 0.f; l[i][1] = 0.f;
            s[i][0] = 0.f; s[i][1] = 0.f;
        }
        int k = beg;
        for (; k + UNR <= end; k += UNR) {
            uv v[UNR];
#pragma unroll
            for (int u = 0; u < UNR; u++) {
                int sn = csr[k + u];
                v[u] = *(const uv*)(xcb + (size_t)sn * C);
            }
#pragma unroll
            for (int u = 0; u < UNR; u++)
#pragma unroll
                for (int i = 0; i < W; i++) {
                    unsigned wd = v[u][i];
                    f2 xv;
                    xv[0] = __uint_as_float(wd << 16);
                    xv[1] = __uint_as_float(wd & 0xffff0000u);
                    f2 a = xv * tl[i];
                    f2 pp;
                    pp[0] = __builtin_amdgcn_exp2f(a[0]);
                    pp[1] = __builtin_amdgcn_exp2f(a[1]);
                    l[i] += pp;
                    s[i] = __builtin_elementwise_fma(pp, xv, s[i]);
                }
        }
        for (; k < end; k++) {
            int sn = csr[k];
            uv vv = *(const uv*)(xcb + (size_t)sn * C);
#pragma unroll
            for (int i = 0; i < W; i++) {
                unsigned wd = vv[i];
                f2 xv;
                xv[0] = __uint_as_float(wd << 16);
                xv[1] = __uint_as_float(wd & 0xffff0000u);
                f2 a = xv * tl[i];
                f2 pp;
                pp[0] = __builtin_amdgcn_exp2f(a[0]);
                pp[1] = __builtin_amdgcn_exp2f(a[1]);
                l[i] += pp;
                s[i] = __builtin_elementwise_fma(pp, xv, s[i]);
            }
        }
        bool has = end > beg;
        usv o;
#pragma unroll
        for (int i = 0; i < W; i++) {
            o[2 * i]     = f2bf(has ? s[i][0] / l[i][0] : 0.f);
            o[2 * i + 1] = f2bf(has ? s[i][1] / l[i][1] : 0.f);
        }
        *(usv*)(out + (size_t)node * C + cb) = o;
    }
}

// ------- dual bf16 MFMA GEMM tile loop (XCD-affinity swizzled), fused LN stats
template <int K, int NT, int NTILES>
__device__ __forceinline__ void gemm_phase(SMem& sm,
    const unsigned short* __restrict__ A1, const unsigned short* __restrict__ B1t,
    const unsigned short* __restrict__ A2, const unsigned short* __restrict__ B2t,
    const float* __restrict__ bias, unsigned short* __restrict__ Co, int M,
    float* __restrict__ stat) {
    int t = threadIdx.x;
    int G = gridDim.x;
    constexpr int MH = 20;                   // ceil(157/8)
    for (int bx = blockIdx.x; bx < 8 * NTILES * MH; bx += G) {
        int xid = bx & 7, q = bx >> 3;
        int n = q % NTILES, mh = q / NTILES;
        int m = mh * 8 + xid;
        if (m * 128 >= MPAD) continue;
        int m0 = m * 128, n0 = n * 128;
        int wv = t >> 6, lane = t & 63;
        int wm = wv & 1, wn = wv >> 1;
        int lm = lane & 15, quad = lane >> 4;
        int sr = t >> 2;
        int sc8 = (t & 3) * 8;
        f32x4 acc[4][4] = {};
        __syncthreads();                     // LDS hazard guard vs prior tile
        for (int ph = 0; ph < 2; ph++) {
            const unsigned short* __restrict__ A  = ph ? A2 : A1;
            const unsigned short* __restrict__ Bt = ph ? B2t : B1t;
            for (int k0 = 0; k0 < K; k0 += 32) {
#pragma unroll
                for (int it = 0; it < 2; it++) {
                    load_lds16(A  + (size_t)(m0 + it * 64 + sr) * K + k0 + sc8,
                               (unsigned short*)&sm.g.As[it * 2048 + wv * 512]);
                    load_lds16(Bt + (size_t)(n0 + it * 64 + sr) * K + k0 + sc8,
                               (unsigned short*)&sm.g.Bs[it * 2048 + wv * 512]);
                }
                __syncthreads();
                bf16x8 af[4], bfr[4];
#pragma unroll
                for (int i = 0; i < 4; i++) {
                    af[i]  = *(const bf16x8*)&sm.g.As[(wm * 64 + i * 16 + lm) * 32 + quad * 8];
                    bfr[i] = *(const bf16x8*)&sm.g.Bs[(wn * 64 + i * 16 + lm) * 32 + quad * 8];
                }
#pragma unroll
                for (int mi = 0; mi < 4; mi++)
#pragma unroll
                    for (int nj = 0; nj < 4; nj++)
                        acc[mi][nj] = __builtin_amdgcn_mfma_f32_16x16x32_bf16(
                            af[mi], bfr[nj], acc[mi][nj], 0, 0, 0);
                __syncthreads();
            }
        }
        float sum = 0.f, ss = 0.f;
#pragma unroll
        for (int mi = 0; mi < 4; mi++) {
            int rb = m0 + wm * 64 + mi * 16 + quad * 4;
#pragma unroll
            for (int nj = 0; nj < 4; nj++) {
                int col = n0 + wn * 64 + nj * 16 + lm;
                float bb = bias[col];
#pragma unroll
                for (int rg = 0; rg < 4; rg++) {
                    int row = rb + rg;
                    if (row < M) {
                        float y = acc[mi][nj][rg] + bb;
                        Co[(size_t)row * NT + col] = f2bf(y);
                        sum += y; ss += y * y;
                    }
                }
            }
        }
        sm.g.rs[t] = sum; sm.g.rq[t] = ss;
        __syncthreads();
        for (int o = 128; o > 0; o >>= 1) {
            if (t < o) { sm.g.rs[t] += sm.g.rs[t + o]; sm.g.rq[t] += sm.g.rq[t + o]; }
            __syncthreads();
        }
        if (t == 0) { atomicAdd(&stat[0], sm.g.rs[0]); atomicAdd(&stat[1], sm.g.rq[0]); }
    }
}

// =================== THE WHOLE PIPELINE, ONE COOPERATIVE DISPATCH ============
__global__ __launch_bounds__(256, 4) void k_mega(Params p) {
    cg::grid_group gg = cg::this_grid();
    __shared__ SMem sm;
    int t = threadIdx.x;
    int bid = blockIdx.x;
    int G = gridDim.x;
    int T = G * 256;
    int gtid = bid * 256 + t;
    int gwave = gtid >> 6;
    int nwaves = T >> 6;

    // P0: zero counts / acc / colsum
    for (int i = gtid; i < NODES; i += T) p.counts[i] = 0;
    if (bid == 0) { if (t < 4) p.acc[t] = 0.f; p.colsum[t] = 0.f; }
    gg.sync();

    // P1: edge count + x cast + 4x weight transpose (independent subtasks)
    for (int e = gtid; e < EDGES; e += T) atomicAdd(&p.counts[p.dst[e]], 1);
    for (int i = gtid; i < NODES * 256 / 4; i += T) {
        float4 v = *(const float4*)(p.x + (size_t)i * 4);
        unsigned short* o = p.xb + (size_t)i * 4;
        o[0] = f2bf(v.x); o[1] = f2bf(v.y); o[2] = f2bf(v.z); o[3] = f2bf(v.w);
    }
    for (int zz = bid; zz < 512; zz += G) {
        int z = zz >> 7, idx = zz & 127;
        const float* W = (z == 0) ? p.Wl1 : (z == 1) ? p.Wr1 : (z == 2) ? p.Wl2 : p.Wr2;
        unsigned short* Wt = (z == 0) ? p.w1lt : (z == 1) ? p.w1rt : (z == 2) ? p.w2lt : p.w2rt;
        int K = (z < 2) ? 256 : 512, N = (z < 2) ? 512 : 256;
        int nb = N / 32;
        int n0 = (idx % nb) * 32, k0 = (idx / nb) * 32;
        int tx = t & 31, ty = t >> 5;
        __syncthreads();
#pragma unroll
        for (int j = 0; j < 4; j++)
            sm.tile[ty + j * 8][tx] = W[(size_t)(k0 + ty + j * 8) * N + n0 + tx];
        __syncthreads();
#pragma unroll
        for (int j = 0; j < 4; j++)
            Wt[(size_t)(n0 + ty + j * 8) * K + k0 + tx] = f2bf(sm.tile[tx][ty + j * 8]);
    }
    gg.sync();

    // P2: CSR scan (block 0 only)
    if (bid == 0) {
        const int chunk = (NODES + 255) / 256;
        int b = t * chunk, e = b + chunk;
        if (b > NODES) b = NODES;
        if (e > NODES) e = NODES;
        int s = 0;
        for (int i = b; i < e; i++) s += p.counts[i];
        sm.ssum[t] = s;
        __syncthreads();
        int v = s;
#pragma unroll
        for (int o = 1; o < 256; o <<= 1) {
            int add = (t >= o) ? sm.ssum[t - o] : 0;
            __syncthreads();
            v += add;
            sm.ssum[t] = v;
            __syncthreads();
        }
        int run = v - s;
        if (t == 255) p.offs[NODES] = v;
        for (int i = b; i < e; i++) { p.offs[i] = run; run += p.counts[i]; }
    }
    gg.sync();

    // P3: scatter (countdown on counts; leaves counts zeroed)
    for (int e = gtid; e < EDGES; e += T) {
        int d = p.dst[e];
        int pos = atomicAdd(&p.counts[d], -1) - 1;
        p.csrc[p.offs[d] + pos] = p.src[e];
    }
    gg.sync();

    // P4: agg1 (2 waves/node, 128 ch each)
    agg_phase<256, 2, 8>(p.xb, p.t1, p.offs, p.csrc, p.aggb, gwave, nwaves);
    gg.sync();

    // P5: gemm1 (+LN1 stats into acc[0..2))
    gemm_phase<256, 512, 4>(sm, p.aggb, p.w1lt, p.xb, p.w1rt, p.bl1, p.h1, NODES, p.acc);
    gg.sync();

    // P6: graph-LN1 + ReLU, in place on h1
    {
        typedef unsigned short us8 __attribute__((ext_vector_type(8)));
        const float invn = 1.f / (float)(NODES * 512);
        float mu = p.acc[0] * invn;
        float var = p.acc[1] * invn - mu * mu;
        var = var < 0.f ? 0.f : var;
        float inv = 1.f / (sqrtf(var) + EPSV);
        for (int i8 = gtid; i8 < NODES * 512 / 8; i8 += T) {
            int i = i8 * 8;
            int c = i & 511;
            us8 v = *(const us8*)(p.h1 + i);
            us8 o;
#pragma unroll
            for (int j = 0; j < 8; j++) {
                float y = (bf2f(v[j]) - mu) * inv * p.g1[c + j] + p.be1[c + j];
                o[j] = f2bf(fmaxf(y, 0.f));
            }
            *(us8*)(p.h1 + i) = o;
        }
    }
    gg.sync();

    // P7: agg2 (2 waves/node, 256 ch each)
    agg_phase<512, 2, 4>(p.h1, p.t2, p.offs, p.csrc, p.aggb, gwave, nwaves);
    gg.sync();

    // P8: gemm2 (+LN2 stats into acc[2..4))
    gemm_phase<512, 256, 2>(sm, p.aggb, p.w2lt, p.h1, p.w2rt, p.bl2, p.h2p, NODES, p.acc + 2);
    gg.sync();

    // P9: graph-LN2 + ReLU + column-sum (<=512 blocks; channel == t)
    {
        int nb9 = G < 512 ? G : 512;
        if (bid < nb9) {
            const int n = NODES * 256;
            const float invn = 1.f / (float)n;
            float mu = p.acc[2] * invn;
            float var = p.acc[3] * invn - mu * mu;
            var = var < 0.f ? 0.f : var;
            float inv = 1.f / (sqrtf(var) + EPSV);
            float gv = p.g2[t], bv = p.be2[t];
            float local = 0.f;
            for (int i = bid * 256 + t; i < n; i += nb9 * 256)
                local += fmaxf((bf2f(p.h2p[i]) - mu) * inv * gv + bv, 0.f);
            atomicAdd(&p.colsum[t], local);
        }
    }
    gg.sync();

    // P10: head — mean-pool @ Wf + bf -> LN(64) -> relu (block 0)
    if (bid == 0) {
        sm.p[t] = p.colsum[t] * (1.0f / (float)NODES);
        __syncthreads();
        if (t < 64) {
            float acc = p.bf[t];
            for (int c = 0; c < 256; c++) acc = fmaf(sm.p[c], p.Wf[c * 64 + t], acc);
            float sum = acc;
            for (int o = 32; o > 0; o >>= 1) sum += __shfl_xor(sum, o);
            float mu = sum * (1.0f / 64.0f);
            float d = acc - mu;
            float vs = d * d;
            for (int o = 32; o > 0; o >>= 1) vs += __shfl_xor(vs, o);
            float var = vs * (1.0f / 64.0f);
            float y = d * rsqrtf(var + EPSV) * p.gx[t] + p.bx[t];
            p.out[t] = fmaxf(y, 0.f);
        }
    }
}

extern "C" void kernel_launch(void* const* d_in, const int* in_sizes, int n_in,
                              void* d_out, int out_size, void* d_ws, size_t ws_size,
                              hipStream_t stream) {
    const int* ei = (const int*)d_in[1];

    char* ws = (char*)d_ws;
    size_t off = 0;
    auto alloc = [&](size_t bytes) { size_t o = off; off = (off + bytes + 511) & ~511ull; return o; };
    size_t o_counts = alloc((size_t)NODES * 4);
    size_t o_acc    = alloc(4 * 4);
    size_t o_colsum = alloc(256 * 4);
    size_t o_offs   = alloc((size_t)(NODES + 1) * 4);
    size_t o_csrc   = alloc((size_t)EDGES * 4);
    size_t o_w1l    = alloc((size_t)512 * 256 * 2);
    size_t o_w1r    = alloc((size_t)512 * 256 * 2);
    size_t o_w2l    = alloc((size_t)256 * 512 * 2);
    size_t o_w2r    = alloc((size_t)256 * 512 * 2);
    size_t o_bufX   = alloc((size_t)MPAD * 256 * 2);        // xb, later h2_pre
    size_t o_agg    = alloc((size_t)MPAD * 512 * 2);        // agg1/agg2
    size_t o_h1     = alloc((size_t)(MPAD + 512) * 512 * 2);

    Params p;
    p.src = ei;
    p.dst = ei + EDGES;
    p.x   = (const float*)d_in[0];
    p.t1  = (const float*)d_in[2];
    p.Wl1 = (const float*)d_in[3];
    p.bl1 = (const float*)d_in[4];
    p.Wr1 = (const float*)d_in[5];
    p.g1  = (const float*)d_in[6];
    p.be1 = (const float*)d_in[7];
    p.t2  = (const float*)d_in[8];
    p.Wl2 = (const float*)d_in[9];
    p.bl2 = (const float*)d_in[10];
    p.Wr2 = (const float*)d_in[11];
    p.g2  = (const float*)d_in[12];
    p.be2 = (const float*)d_in[13];
    p.Wf  = (const float*)d_in[14];
    p.bf  = (const float*)d_in[15];
    p.gx  = (const float*)d_in[16];
    p.bx  = (const float*)d_in[17];
    p.out = (float*)d_out;
    p.counts = (int*)(ws + o_counts);
    p.offs   = (int*)(ws + o_offs);
    p.csrc   = (int*)(ws + o_csrc);
    p.acc    = (float*)(ws + o_acc);
    p.colsum = (float*)(ws + o_colsum);
    p.w1lt = (unsigned short*)(ws + o_w1l);
    p.w1rt = (unsigned short*)(ws + o_w1r);
    p.w2lt = (unsigned short*)(ws + o_w2l);
    p.w2rt = (unsigned short*)(ws + o_w2r);
    p.xb   = (unsigned short*)(ws + o_bufX);
    p.h2p  = (unsigned short*)(ws + o_bufX);   // reuse after xb dead (post-P5)
    p.aggb = (unsigned short*)(ws + o_agg);
    p.h1   = (unsigned short*)(ws + o_h1);

    int nb = 0;
    if (hipOccupancyMaxActiveBlocksPerMultiprocessor(&nb, k_mega, 256, 0) != hipSuccess || nb < 1)
        nb = 2;
    int G = nb * 256;            // 256 CUs on MI355X
    if (G > 1024) G = 1024;

    void* args[] = { &p };
    hipLaunchCooperativeKernel((const void*)k_mega, dim3(G), dim3(256), args, 0, stream);
}

// Round 12
// 346.028 us; speedup vs baseline: 3.1788x; 3.1788x over previous
//
#include <hip/hip_runtime.h>
#include <math.h>

#define NODES 20000
#define MPAD  20096          // NODES padded to multiple of 128 (GEMM M-tiles)
#define EDGES 320000
#define EPSV  1e-5f
#define LOG2E 1.4426950408889634f

// k_prep block ranges
#define PREP_CNT   1250                    // count: 1250*256 >= EDGES
#define PREP_CAST  5000                    // cast: NODES*256/4/256
#define PREP_TR    512                     // 4 matrices * 128 tiles
#define PREP_TOTAL (PREP_CNT + PREP_CAST + PREP_TR + 1)

typedef short bf16x8 __attribute__((ext_vector_type(8)));
typedef float f32x4  __attribute__((ext_vector_type(4)));
typedef float f2     __attribute__((ext_vector_type(2)));

__device__ __forceinline__ unsigned short f2bf(float f) {
    unsigned int u = __float_as_uint(f);
    u = (u + 0x7fffu + ((u >> 16) & 1u)) >> 16;
    return (unsigned short)u;
}
__device__ __forceinline__ float bf2f(unsigned short h) {
    return __uint_as_float(((unsigned int)h) << 16);
}

// async global->LDS, 16B per lane; lds dest = wave-uniform base + lane*16
__device__ __forceinline__ void load_lds16(const unsigned short* g, unsigned short* l) {
    __builtin_amdgcn_global_load_lds(
        (const __attribute__((address_space(1))) unsigned int*)g,
        (__attribute__((address_space(3))) unsigned int*)l, 16, 0, 0);
}

// ---------------- fused prep: edge-count + x cast + 4x weight transpose + zeros
__global__ void k_prep(const int* __restrict__ dst, int* __restrict__ counts,
                       const float* __restrict__ x, unsigned short* __restrict__ xb,
                       const float* __restrict__ Wl1, const float* __restrict__ Wr1,
                       const float* __restrict__ Wl2, const float* __restrict__ Wr2,
                       unsigned short* __restrict__ o1l, unsigned short* __restrict__ o1r,
                       unsigned short* __restrict__ o2l, unsigned short* __restrict__ o2r,
                       float* __restrict__ acc, float* __restrict__ colsum) {
    int b = blockIdx.x;
    int t = threadIdx.x;
    if (b < PREP_CNT) {
        int e = b * 256 + t;
        if (e < EDGES) atomicAdd(&counts[dst[e]], 1);
    } else if (b < PREP_CNT + PREP_CAST) {
        int i = ((b - PREP_CNT) * 256 + t) * 4;
        float4 v = *(const float4*)(x + i);
        xb[i + 0] = f2bf(v.x); xb[i + 1] = f2bf(v.y);
        xb[i + 2] = f2bf(v.z); xb[i + 3] = f2bf(v.w);
    } else if (b < PREP_CNT + PREP_CAST + PREP_TR) {
        __shared__ float tile[32][33];
        int zz = b - PREP_CNT - PREP_CAST;     // 0..511
        int z = zz >> 7;                        // matrix 0..3
        int idx = zz & 127;                     // tile within matrix
        const float* W = (z == 0) ? Wl1 : (z == 1) ? Wr1 : (z == 2) ? Wl2 : Wr2;
        unsigned short* Wt = (z == 0) ? o1l : (z == 1) ? o1r : (z == 2) ? o2l : o2r;
        int K = (z < 2) ? 256 : 512, N = (z < 2) ? 512 : 256;
        int nb = N / 32;
        int n0 = (idx % nb) * 32, k0 = (idx / nb) * 32;
        int tx = t & 31, ty = t >> 5;          // (32,8) layout
#pragma unroll
        for (int j = 0; j < 4; j++)
            tile[ty + j * 8][tx] = W[(size_t)(k0 + ty + j * 8) * N + n0 + tx];
        __syncthreads();
#pragma unroll
        for (int j = 0; j < 4; j++)
            Wt[(size_t)(n0 + ty + j * 8) * K + k0 + tx] = f2bf(tile[tx][ty + j * 8]);
    } else {
        if (t < 4) acc[t] = 0.f;
        colsum[t] = 0.f;
    }
}

// ---------------- CSR scan + scatter ----------------
__global__ void k_scan(const int* __restrict__ counts, int* __restrict__ offs) {
    __shared__ int ssum[256];
    int t = threadIdx.x;
    const int chunk = (NODES + 255) / 256;
    int b = t * chunk, e = b + chunk;
    if (b > NODES) b = NODES;
    if (e > NODES) e = NODES;
    int s = 0;
    for (int i = b; i < e; i++) s += counts[i];
    ssum[t] = s;
    __syncthreads();
    int v = s;
#pragma unroll
    for (int o = 1; o < 256; o <<= 1) {
        int add = (t >= o) ? ssum[t - o] : 0;
        __syncthreads();
        v += add;
        ssum[t] = v;
        __syncthreads();
    }
    int run = v - s;
    if (t == 255) offs[NODES] = v;
    for (int i = b; i < e; i++) { offs[i] = run; run += counts[i]; }
}

__global__ void k_scatter(const int* __restrict__ src, const int* __restrict__ dst,
                          const int* __restrict__ offs, int* __restrict__ cursor,
                          int* __restrict__ csr_src) {
    int e = blockIdx.x * blockDim.x + threadIdx.x;
    if (e < EDGES) {
        int d = dst[e];
        int pos = atomicAdd(&cursor[d], 1);
        csr_src[offs[d] + pos] = src[e];
    }
}

// ------- per-channel softmax aggregation, un-stabilized, XCD-affine + packed -
// slice = blockIdx % S (CS = 128 channels = 256B stripe). Per-slice working set
// 20000*128*2B = 5.1MB lands on NODES round-robin XCDs (S=4 -> 2 XCDs/slice,
// 8MB L2; S=2 -> 4 XCDs). Keeps VPL=2 packed-f32 math (r9 lesson: VPL=1 scalar
// slicing lost more on issue than it gained on latency). Wave-uniform CSR walk
// via readfirstlane: csr[k] -> s_load, row base math on SALU.
template <int C, int S, int UNR>
__global__ void k_agg_x(const unsigned short* __restrict__ xb, const float* __restrict__ tt,
                        const int* __restrict__ offs, const int* __restrict__ csr,
                        unsigned short* __restrict__ out) {
    static_assert(C / S == 128, "CS must be 128 (VPL=2 packed)");
    int t = threadIdx.x;
    int lane = t & 63;
    int slice = blockIdx.x % S;
    int node = (blockIdx.x / S) * 4 + (t >> 6);
    if (node >= NODES) return;
    int beg = __builtin_amdgcn_readfirstlane(offs[node]);
    int end = __builtin_amdgcn_readfirstlane(offs[node + 1]);
    int cb = slice * 128 + lane * 2;
    const unsigned short* __restrict__ xcb = xb + cb;   // per-lane, loop-invariant
    f2 tl, l, s;
    tl[0] = tt[cb] * LOG2E;
    tl[1] = tt[cb + 1] * LOG2E;
    l[0] = 0.f; l[1] = 0.f;
    s[0] = 0.f; s[1] = 0.f;
    int k = beg;
    for (; k + UNR <= end; k += UNR) {
        unsigned d[UNR];
#pragma unroll
        for (int u = 0; u < UNR; u++) {
            int sn = csr[k + u];                         // uniform -> s_load
            d[u] = *(const unsigned*)(xcb + (size_t)sn * C);
        }
#pragma unroll
        for (int u = 0; u < UNR; u++) {
            unsigned wd = d[u];
            f2 xv;
            xv[0] = __uint_as_float(wd << 16);
            xv[1] = __uint_as_float(wd & 0xffff0000u);
            f2 a = xv * tl;
            f2 p;
            p[0] = __builtin_amdgcn_exp2f(a[0]);
            p[1] = __builtin_amdgcn_exp2f(a[1]);
            l += p;
            s = __builtin_elementwise_fma(p, xv, s);
        }
    }
    for (; k < end; k++) {
        int sn = csr[k];
        unsigned wd = *(const unsigned*)(xcb + (size_t)sn * C);
        f2 xv;
        xv[0] = __uint_as_float(wd << 16);
        xv[1] = __uint_as_float(wd & 0xffff0000u);
        f2 a = xv * tl;
        f2 p;
        p[0] = __builtin_amdgcn_exp2f(a[0]);
        p[1] = __builtin_amdgcn_exp2f(a[1]);
        l += p;
        s = __builtin_elementwise_fma(p, xv, s);
    }
    bool has = end > beg;
    unsigned o = (unsigned)f2bf(has ? s[0] / l[0] : 0.f)
               | ((unsigned)f2bf(has ? s[1] / l[1] : 0.f) << 16);
    *(unsigned*)(out + (size_t)node * C + cb) = o;
}

// ---------------- dual bf16 MFMA GEMM: C = A1*B1t^T + A2*B2t^T + bias ---------
// 1D grid with XCD-affinity swizzle: all NTILES n-variants of one m-tile map
// to the SAME bx%8 (=XCD) so the re-staged A-tile stays L2-resident.
template <int K, int NT, int NTILES>
__global__ __launch_bounds__(256) void k_gemm_mfma(
    const unsigned short* __restrict__ A1, const unsigned short* __restrict__ B1t,
    const unsigned short* __restrict__ A2, const unsigned short* __restrict__ B2t,
    const float* __restrict__ bias, unsigned short* __restrict__ Co, int M,
    float* __restrict__ stat) {
    __shared__ short As[128 * 32];
    __shared__ short Bs[128 * 32];
    __shared__ float rs[256], rq[256];

    // swizzled decode: bx = x + 8*(n + NTILES*mh); m = mh*8 + x
    int bx = blockIdx.x;
    int xid = bx & 7, q = bx >> 3;
    int n = q % NTILES, mh = q / NTILES;
    int m = mh * 8 + xid;
    if (m * 128 >= MPAD) return;           // pad tiles: whole block exits
    int m0 = m * 128, n0 = n * 128;

    int t = threadIdx.x;
    int wv = t >> 6, lane = t & 63;
    int wm = wv & 1, wn = wv >> 1;
    int lm = lane & 15, quad = lane >> 4;
    int sr = t >> 2;
    int sc8 = (t & 3) * 8;

    f32x4 acc[4][4] = {};

    for (int ph = 0; ph < 2; ph++) {
        const unsigned short* __restrict__ A  = ph ? A2 : A1;
        const unsigned short* __restrict__ Bt = ph ? B2t : B1t;
        for (int k0 = 0; k0 < K; k0 += 32) {
#pragma unroll
            for (int it = 0; it < 2; it++) {
                load_lds16(A  + (size_t)(m0 + it * 64 + sr) * K + k0 + sc8,
                           (unsigned short*)&As[it * 2048 + wv * 512]);
                load_lds16(Bt + (size_t)(n0 + it * 64 + sr) * K + k0 + sc8,
                           (unsigned short*)&Bs[it * 2048 + wv * 512]);
            }
            __syncthreads();
            bf16x8 af[4], bfr[4];
#pragma unroll
            for (int i = 0; i < 4; i++) {
                af[i]  = *(const bf16x8*)&As[(wm * 64 + i * 16 + lm) * 32 + quad * 8];
                bfr[i] = *(const bf16x8*)&Bs[(wn * 64 + i * 16 + lm) * 32 + quad * 8];
            }
#pragma unroll
            for (int mi = 0; mi < 4; mi++)
#pragma unroll
                for (int nj = 0; nj < 4; nj++)
                    acc[mi][nj] = __builtin_amdgcn_mfma_f32_16x16x32_bf16(
                        af[mi], bfr[nj], acc[mi][nj], 0, 0, 0);
            __syncthreads();
        }
    }

    float sum = 0.f, ss = 0.f;
#pragma unroll
    for (int mi = 0; mi < 4; mi++) {
        int rb = m0 + wm * 64 + mi * 16 + quad * 4;
#pragma unroll
        for (int nj = 0; nj < 4; nj++) {
            int col = n0 + wn * 64 + nj * 16 + lm;
            float bb = bias[col];
#pragma unroll
            for (int rg = 0; rg < 4; rg++) {
                int row = rb + rg;
                if (row < M) {
                    float y = acc[mi][nj][rg] + bb;
                    Co[(size_t)row * NT + col] = f2bf(y);
                    sum += y; ss += y * y;
                }
            }
        }
    }
    rs[t] = sum; rq[t] = ss;
    __syncthreads();
    for (int o = 128; o > 0; o >>= 1) {
        if (t < o) { rs[t] += rs[t + o]; rq[t] += rq[t + o]; }
        __syncthreads();
    }
    if (t == 0) { atomicAdd(&stat[0], rs[0]); atomicAdd(&stat[1], rq[0]); }
}

// ---------------- graph-LN + ReLU, in-place bf16, vectorized x8 --------------
template <int C>
__global__ void k_ln_relu_b(unsigned short* __restrict__ h, int n,
                            const float* __restrict__ st,
                            const float* __restrict__ g, const float* __restrict__ b) {
    typedef unsigned short us8 __attribute__((ext_vector_type(8)));
    float mu = st[0] / (float)n;
    float var = st[1] / (float)n - mu * mu;
    var = var < 0.f ? 0.f : var;
    float inv = 1.0f / (sqrtf(var) + EPSV);
    int i8 = (blockIdx.x * blockDim.x + threadIdx.x) * 8;
    if (i8 >= n) return;
    int c = i8 & (C - 1);
    us8 v = *(const us8*)(h + i8);
    us8 o;
#pragma unroll
    for (int j = 0; j < 8; j++) {
        float y = (bf2f(v[j]) - mu) * inv * g[c + j] + b[c + j];
        o[j] = f2bf(fmaxf(y, 0.f));
    }
    *(us8*)(h + i8) = o;
}

// graph-LN + ReLU + column-sum only (layer 2; h2 not needed afterwards)
__global__ void k_ln_colsum(const unsigned short* __restrict__ h, int n,
                            const float* __restrict__ st,
                            const float* __restrict__ g, const float* __restrict__ b,
                            float* __restrict__ colsum) {
    float mu = st[0] / (float)n;
    float var = st[1] / (float)n - mu * mu;
    var = var < 0.f ? 0.f : var;
    float inv = 1.0f / (sqrtf(var) + EPSV);
    int t = threadIdx.x;
    float gv = g[t], bv = b[t];
    float local = 0.f;
    int stride = gridDim.x * blockDim.x;   // multiple of 256 -> channel == t always
    for (int i = blockIdx.x * blockDim.x + t; i < n; i += stride) {
        float y = (bf2f(h[i]) - mu) * inv * gv + bv;
        local += fmaxf(y, 0.f);
    }
    atomicAdd(&colsum[t], local);
}

// ---------------- head: mean-pool @ Wf + bf -> LN(64) -> relu ----------------
__global__ void k_final(const float* __restrict__ colsum, const float* __restrict__ Wf,
                        const float* __restrict__ bf, const float* __restrict__ gx,
                        const float* __restrict__ bx, float* __restrict__ out) {
    __shared__ float p[256];
    int t = threadIdx.x;
    p[t] = colsum[t] * (1.0f / (float)NODES);
    __syncthreads();
    if (t < 64) {
        float acc = bf[t];
        for (int c = 0; c < 256; c++) acc = fmaf(p[c], Wf[c * 64 + t], acc);
        float sum = acc;
        for (int o = 32; o > 0; o >>= 1) sum += __shfl_xor(sum, o);
        float mu = sum * (1.0f / 64.0f);
        float d = acc - mu;
        float vs = d * d;
        for (int o = 32; o > 0; o >>= 1) vs += __shfl_xor(vs, o);
        float var = vs * (1.0f / 64.0f);
        float y = d * rsqrtf(var + EPSV) * gx[t] + bx[t];
        out[t] = fmaxf(y, 0.f);
    }
}

extern "C" void kernel_launch(void* const* d_in, const int* in_sizes, int n_in,
                              void* d_out, int out_size, void* d_ws, size_t ws_size,
                              hipStream_t stream) {
    const float* x   = (const float*)d_in[0];
    const int*   ei  = (const int*)d_in[1];
    const float* t1  = (const float*)d_in[2];
    const float* Wl1 = (const float*)d_in[3];
    const float* bl1 = (const float*)d_in[4];
    const float* Wr1 = (const float*)d_in[5];
    const float* g1  = (const float*)d_in[6];
    const float* be1 = (const float*)d_in[7];
    const float* t2  = (const float*)d_in[8];
    const float* Wl2 = (const float*)d_in[9];
    const float* bl2 = (const float*)d_in[10];
    const float* Wr2 = (const float*)d_in[11];
    const float* g2  = (const float*)d_in[12];
    const float* be2 = (const float*)d_in[13];
    const float* Wf  = (const float*)d_in[14];
    const float* bf  = (const float*)d_in[15];
    const float* gx  = (const float*)d_in[16];
    const float* bx  = (const float*)d_in[17];
    float* out = (float*)d_out;

    char* ws = (char*)d_ws;
    size_t off = 0;
    auto alloc = [&](size_t bytes) { size_t o = off; off = (off + bytes + 511) & ~511ull; return o; };
    size_t o_counts = alloc((size_t)NODES * 4);
    size_t o_cursor = alloc((size_t)NODES * 4);
    size_t zero_bytes = off;                         // memset: counts+cursor only
    size_t o_acc    = alloc(4 * 4);
    size_t o_colsum = alloc(256 * 4);
    size_t o_offs = alloc((size_t)(NODES + 1) * 4);
    size_t o_csrc = alloc((size_t)EDGES * 4);
    size_t o_w1l  = alloc((size_t)512 * 256 * 2);
    size_t o_w1r  = alloc((size_t)512 * 256 * 2);
    size_t o_w2l  = alloc((size_t)256 * 512 * 2);
    size_t o_w2r  = alloc((size_t)256 * 512 * 2);
    size_t o_bufX = alloc((size_t)MPAD * 256 * 2);   // xb, later h2_pre (bf16)
    size_t o_agg  = alloc((size_t)MPAD * 512 * 2);   // agg1b / agg2b
    size_t o_h1   = alloc((size_t)(MPAD + 512) * 512 * 2); // h1 (+pad-tile slack)

    int*   counts = (int*)(ws + o_counts);
    int*   cursor = (int*)(ws + o_cursor);
    float* acc    = (float*)(ws + o_acc);      // [0,1]=L1 stats, [2,3]=L2 stats
    float* colsum = (float*)(ws + o_colsum);
    int*   offs   = (int*)(ws + o_offs);
    int*   csrc   = (int*)(ws + o_csrc);
    unsigned short* w1lt = (unsigned short*)(ws + o_w1l);
    unsigned short* w1rt = (unsigned short*)(ws + o_w1r);
    unsigned short* w2lt = (unsigned short*)(ws + o_w2l);
    unsigned short* w2rt = (unsigned short*)(ws + o_w2r);
    unsigned short* xb   = (unsigned short*)(ws + o_bufX);
    unsigned short* h2p  = (unsigned short*)(ws + o_bufX);  // reuse after xb dead
    unsigned short* aggb = (unsigned short*)(ws + o_agg);
    unsigned short* h1   = (unsigned short*)(ws + o_h1);

    const int* src = ei;
    const int* dst = ei + EDGES;

    hipMemsetAsync(ws, 0, zero_bytes, stream);

    // D1: fused prep (count + cast + transposes + zero acc/colsum)
    k_prep<<<PREP_TOTAL, 256, 0, stream>>>(dst, counts, x, xb,
                                           Wl1, Wr1, Wl2, Wr2,
                                           w1lt, w1rt, w2lt, w2rt,
                                           acc, colsum);
    // D2/D3: CSR
    k_scan<<<1, 256, 0, stream>>>(counts, offs);
    k_scatter<<<(EDGES + 255) / 256, 256, 0, stream>>>(src, dst, offs, cursor, csrc);

    // ----- layer 1 -----  (2 slices/node of 128 ch; slice = blockIdx % 2)
    k_agg_x<256, 2, 8><<<(NODES / 4) * 2, 256, 0, stream>>>(xb, t1, offs, csrc, aggb);
    k_gemm_mfma<256, 512, 4><<<8 * 4 * 20, 256, 0, stream>>>(
        aggb, w1lt, xb, w1rt, bl1, h1, NODES, acc);
    k_ln_relu_b<512><<<NODES * 512 / 8 / 256, 256, 0, stream>>>(h1, NODES * 512, acc, g1, be1);

    // ----- layer 2 -----  (4 slices/node of 128 ch; slice = blockIdx % 4 -> XCD pair)
    k_agg_x<512, 4, 8><<<(NODES / 4) * 4, 256, 0, stream>>>(h1, t2, offs, csrc, aggb);
    k_gemm_mfma<512, 256, 2><<<8 * 2 * 20, 256, 0, stream>>>(
        aggb, w2lt, h1, w2rt, bl2, h2p, NODES, acc + 2);

    // ----- LN2 + colsum, then head -----
    k_ln_colsum<<<1024, 256, 0, stream>>>(h2p, NODES * 256, acc + 2, g2, be2, colsum);
    k_final<<<1, 256, 0, stream>>>(colsum, Wf, bf, gx, bx, out);
}